// Round 4
// baseline (35.344 us; speedup 1.0000x reference)
//
#include <hip/hip_runtime.h>
#include <math.h>

#define HB 16
#define CB 64
#define HH 128
#define WW 128

// LDS tile: 36 rows (32 outputs + 2 halo each side) x 136 cols (128 + 4 halo each side)
#define LROWS 36
#define LCOLS 136              // 34 float4 slots; stride 544 B (16B-aligned)
#define LELEM (LROWS * LCOLS)  // 4896 floats = 19584 B
#define LQUADS (LROWS * (LCOLS / 4))  // 1224 float4 slots

__global__ __launch_bounds__(256) void morpho_kernel(
    const float* __restrict__ x,     // [B,C,128,128]
    const float* __restrict__ w,     // [B,C,5,5]
    const float* __restrict__ bias,  // [B,C]
    const float* __restrict__ sign,  // [B]
    float* __restrict__ out)         // [B,C,128,128]
{
    __shared__ float lds[LELEM];

    const int blk  = blockIdx.x;
    const int quad = blk & 3;        // 32-row band
    const int bc   = blk >> 2;       // plane = b*64 + c
    const int b    = bc >> 6;

    const float* __restrict__ xp = x   + (size_t)bc * (HH * WW);
    float*       __restrict__ yp = out + (size_t)bc * (HH * WW);
    const float* __restrict__ wp = w   + bc * 25;

    const float sgn = sign[b];
    const float s   = (fabsf(sgn) >= 1e-7f) ? sgn : 1.0f;
    const float bv  = bias[bc];

    const int t       = threadIdx.x;
    const int rowbase = quad * 32 - 2;   // global row of LDS row 0

    // ---- stage: 1224 float4 slots, 5 per thread; prescale by s, zero-pad OOB ----
#pragma unroll
    for (int k = 0; k < 5; ++k) {
        const int i = k * 256 + t;
        if (i < LQUADS) {
            const int r    = i / 34;          // LDS row 0..35
            const int c4   = i - r * 34;      // float4 slot 0..33
            const int grow = rowbase + r;     // global row
            const int gcol = c4 * 4 - 4;      // global col of slot start
            const bool valid = ((unsigned)grow < (unsigned)HH) &&
                               ((unsigned)(c4 - 1) < 32u);
            const float sm = valid ? s : 0.f;
            // clamped in-plane address -> unconditional, hoistable load
            const int rc = min(max(grow, 0), HH - 1);
            const int cc = min(max(gcol, 0), WW - 4);
            const float4 v = *reinterpret_cast<const float4*>(xp + rc * WW + cc);
            float4 o;
            o.x = v.x * sm; o.y = v.y * sm; o.z = v.z * sm; o.w = v.w * sm;
            *reinterpret_cast<float4*>(&lds[r * LCOLS + c4 * 4]) = o;
        }
    }

    // weights while staging loads are in flight (block-uniform -> s_load)
    float wv[25];
#pragma unroll
    for (int k = 0; k < 25; ++k) wv[k] = wp[k];

    __syncthreads();

    const int tx = t & 31;           // col-block (4 output cols)
    const int ty = t >> 5;           // 0..7 (4 output rows each)
    const int j0 = tx * 4;
    const int i0 = quad * 32 + ty * 4;

    float acc[4][4];                 // first-touch at p==0

#pragma unroll
    for (int r8 = 0; r8 < 8; ++r8) {
        // LDS row for this input row; cols tx*4 .. tx*4+11 == global j0-4 .. j0+7
        const float* lp = &lds[(ty * 4 + r8) * LCOLS + tx * 4];
        const float4 a0 = *reinterpret_cast<const float4*>(lp);
        const float4 a1 = *reinterpret_cast<const float4*>(lp + 4);
        const float4 a2 = *reinterpret_cast<const float4*>(lp + 8);
        float xr[12];
        xr[0] = a0.x; xr[1] = a0.y; xr[2]  = a0.z; xr[3]  = a0.w;
        xr[4] = a1.x; xr[5] = a1.y; xr[6]  = a1.z; xr[7]  = a1.w;
        xr[8] = a2.x; xr[9] = a2.y; xr[10] = a2.z; xr[11] = a2.w;

#pragma unroll
        for (int p = 0; p < 5; ++p) {
            const int oi = r8 - p;   // output row in 4-row tile fed by this input row
            if (oi >= 0 && oi < 4) {
#pragma unroll
                for (int oj = 0; oj < 4; ++oj) {
                    // input col = j0 + oj + q - 2 -> xr index oj + q + 2
                    const float t0 = xr[oj + 2] + wv[p * 5 + 0];
                    const float t1 = xr[oj + 3] + wv[p * 5 + 1];
                    const float t2 = xr[oj + 4] + wv[p * 5 + 2];
                    const float t3 = xr[oj + 5] + wv[p * 5 + 3];
                    const float t4 = xr[oj + 6] + wv[p * 5 + 4];
                    float m;
                    if (p == 0) {
                        m = fmaxf(fmaxf(t0, t1), t2);   // -> v_max3
                        m = fmaxf(fmaxf(m, t3), t4);    // -> v_max3
                    } else {
                        m = acc[oi][oj];
                        m = fmaxf(fmaxf(m, t0), t1);    // -> v_max3
                        m = fmaxf(fmaxf(m, t2), t3);    // -> v_max3
                        m = fmaxf(m, t4);
                    }
                    acc[oi][oj] = m;
                }
            }
        }
    }

#pragma unroll
    for (int a = 0; a < 4; ++a) {
        float4 o;
        o.x = (acc[a][0] + bv) * s;
        o.y = (acc[a][1] + bv) * s;
        o.z = (acc[a][2] + bv) * s;
        o.w = (acc[a][3] + bv) * s;
        *reinterpret_cast<float4*>(yp + (size_t)(i0 + a) * WW + j0) = o;
    }
}

extern "C" void kernel_launch(void* const* d_in, const int* in_sizes, int n_in,
                              void* d_out, int out_size, void* d_ws, size_t ws_size,
                              hipStream_t stream) {
    const float* x    = (const float*)d_in[0];
    const float* w    = (const float*)d_in[1];
    const float* bias = (const float*)d_in[2];
    const float* sign = (const float*)d_in[3];
    float* out = (float*)d_out;

    const int planes = HB * CB;      // 1024
    const int grid   = planes * 4;   // 4 row-bands per plane
    morpho_kernel<<<grid, 256, 0, stream>>>(x, w, bias, sign, out);
}

// Round 5
// 30.792 us; speedup vs baseline: 1.1478x; 1.1478x over previous
//
#include <hip/hip_runtime.h>
#include <math.h>
#include <stdint.h>

#define HH 128
#define WW 128
#define LROWS 36
#define LCOLS 136            // floats per LDS row: 128 + 4 halo each side
#define LSLOTS 1224          // 36*34 float4 slots per buffer
#define LFLOATS 4896         // 36*136 floats per buffer

__device__ __forceinline__ void gload_lds16(const float* gp, float* lp) {
    __builtin_amdgcn_global_load_lds(
        (const __attribute__((address_space(1))) void*)gp,
        (__attribute__((address_space(3))) void*)lp,
        16, 0, 0);
}

__global__ __launch_bounds__(256) void morpho_kernel(
    const float* __restrict__ x,     // [B,C,128,128]
    const float* __restrict__ wgt,   // [B,C,5,5]
    const float* __restrict__ bias,  // [B,C]
    const float* __restrict__ sign,  // [B]
    float* __restrict__ out)         // [B,C,128,128]
{
    __shared__ float lds[2][LFLOATS];

    const int bc = blockIdx.x;       // plane 0..1023, one plane per block
    const int b  = bc >> 6;

    const float* __restrict__ xp = x   + (size_t)bc * (HH * WW);
    float*       __restrict__ yp = out + (size_t)bc * (HH * WW);
    const float* __restrict__ wp = wgt + bc * 25;

    const float sgn = sign[b];
    const float s   = (fabsf(sgn) >= 1e-7f) ? sgn : 1.0f;
    const float bvs = bias[bc] * s;

    const int t  = threadIdx.x;
    const int tx = t & 31;           // 4-col block
    const int ty = t >> 5;           // 0..7

    // per-thread staging slot geometry (tile-invariant)
    int  srow[5], goff[5];
    bool scolpad[5], sexist[5];
#pragma unroll
    for (int k = 0; k < 5; ++k) {
        const int i = k * 256 + t;
        sexist[k] = (i < LSLOTS);
        const int r  = i / 34;
        const int c4 = i - r * 34;
        srow[k]    = r;
        scolpad[k] = (c4 == 0) || (c4 == 33);
        goff[k]    = min(max(c4 * 4 - 4, 0), WW - 4);   // clamped col start
    }

    float wv[25];                    // block-uniform -> SGPRs (R4 evidence)
#pragma unroll
    for (int k2 = 0; k2 < 25; ++k2) wv[k2] = wp[k2];

    // issue 5 global_load_lds for one 36-row band (raw x, clamped addrs)
    auto STAGE = [&](int nb, int tile) {
#pragma unroll
        for (int k = 0; k < 5; ++k) {
            if (sexist[k]) {
                const int grow = tile * 32 - 2 + srow[k];
                const int rc   = min(max(grow, 0), HH - 1);
                const float* gp = xp + rc * WW + goff[k];
                const int slotbase = k * 256 + (t & 192);   // wave-uniform
                gload_lds16(gp, &lds[nb][slotbase * 4]);
            }
        }
    };

    // overwrite this thread's pad slots with zeros (own loads already landed)
    auto FIXUP = [&](int cb, int tile) {
#pragma unroll
        for (int k = 0; k < 5; ++k) {
            const int grow = tile * 32 - 2 + srow[k];
            const bool pad = scolpad[k] || (grow < 0) || (grow > HH - 1);
            if (sexist[k] && pad) {
                const int i = k * 256 + t;
                *reinterpret_cast<float4*>(&lds[cb][i * 4]) =
                    make_float4(0.f, 0.f, 0.f, 0.f);
            }
        }
    };

    auto COMPUTE = [&](int cb, int tile) {
        float acc[4][4];
#pragma unroll
        for (int r8 = 0; r8 < 8; ++r8) {
            const float* lp = &lds[cb][(ty * 4 + r8) * LCOLS + tx * 4];
            const float4 a0 = *reinterpret_cast<const float4*>(lp);
            const float4 a1 = *reinterpret_cast<const float4*>(lp + 4);
            const float4 a2 = *reinterpret_cast<const float4*>(lp + 8);
            float xr[12] = {a0.x, a0.y, a0.z, a0.w,
                            a1.x, a1.y, a1.z, a1.w,
                            a2.x, a2.y, a2.z, a2.w};
#pragma unroll
            for (int p = 0; p < 5; ++p) {
                const int oi = r8 - p;
                if (oi >= 0 && oi < 4) {
#pragma unroll
                    for (int oj = 0; oj < 4; ++oj) {
                        // tap = x*s + w  (scale fused into FMA; pad x==0 -> w)
                        const float t0 = fmaf(xr[oj + 2], s, wv[p * 5 + 0]);
                        const float t1 = fmaf(xr[oj + 3], s, wv[p * 5 + 1]);
                        const float t2 = fmaf(xr[oj + 4], s, wv[p * 5 + 2]);
                        const float t3 = fmaf(xr[oj + 5], s, wv[p * 5 + 3]);
                        const float t4 = fmaf(xr[oj + 6], s, wv[p * 5 + 4]);
                        float m;
                        if (p == 0) {
                            m = fmaxf(fmaxf(t0, t1), t2);   // v_max3
                            m = fmaxf(fmaxf(m, t3), t4);    // v_max3
                        } else {
                            m = acc[oi][oj];
                            m = fmaxf(fmaxf(m, t0), t1);
                            m = fmaxf(fmaxf(m, t2), t3);
                            m = fmaxf(m, t4);
                        }
                        acc[oi][oj] = m;
                    }
                }
            }
        }
        const int i0 = tile * 32 + ty * 4;
#pragma unroll
        for (int a = 0; a < 4; ++a) {
            float4 o;
            o.x = fmaf(acc[a][0], s, bvs);   // (acc+bias)*s == acc*s + bias*s
            o.y = fmaf(acc[a][1], s, bvs);
            o.z = fmaf(acc[a][2], s, bvs);
            o.w = fmaf(acc[a][3], s, bvs);
            *reinterpret_cast<float4*>(yp + (size_t)(i0 + a) * WW + tx * 4) = o;
        }
    };

    // ---- software pipeline over 4 band-tiles, double-buffered ----
    // per wave per tile: exactly 5 global_load_lds + 4 global_store_dwordx4
    STAGE(0, 0);
    STAGE(1, 1);
    // tile 0: outstanding [L0(5), L1(5)] -> drain L0
    asm volatile("s_waitcnt vmcnt(5) lgkmcnt(0)" ::: "memory");
    FIXUP(0, 0);
    asm volatile("s_waitcnt lgkmcnt(0)" ::: "memory");
    __builtin_amdgcn_s_barrier();
    COMPUTE(0, 0);
    asm volatile("" ::: "memory");
    __builtin_amdgcn_s_barrier();

    STAGE(0, 2);
    // tile 1: outstanding [L1(5), S0(4), L2(5)] -> drain L1
    asm volatile("s_waitcnt vmcnt(9) lgkmcnt(0)" ::: "memory");
    FIXUP(1, 1);
    asm volatile("s_waitcnt lgkmcnt(0)" ::: "memory");
    __builtin_amdgcn_s_barrier();
    COMPUTE(1, 1);
    asm volatile("" ::: "memory");
    __builtin_amdgcn_s_barrier();

    STAGE(1, 3);
    // tile 2: outstanding [L2(5), S1(4), L3(5)] -> drain L2
    asm volatile("s_waitcnt vmcnt(9) lgkmcnt(0)" ::: "memory");
    FIXUP(0, 2);
    asm volatile("s_waitcnt lgkmcnt(0)" ::: "memory");
    __builtin_amdgcn_s_barrier();
    COMPUTE(0, 2);
    asm volatile("" ::: "memory");
    __builtin_amdgcn_s_barrier();

    // tile 3: outstanding [L3(5), S2(4)] -> drain L3
    asm volatile("s_waitcnt vmcnt(4) lgkmcnt(0)" ::: "memory");
    FIXUP(1, 3);
    asm volatile("s_waitcnt lgkmcnt(0)" ::: "memory");
    __builtin_amdgcn_s_barrier();
    COMPUTE(1, 3);
}

extern "C" void kernel_launch(void* const* d_in, const int* in_sizes, int n_in,
                              void* d_out, int out_size, void* d_ws, size_t ws_size,
                              hipStream_t stream) {
    (void)d_ws; (void)ws_size; (void)in_sizes; (void)n_in; (void)out_size;
    const float* x    = (const float*)d_in[0];
    const float* w    = (const float*)d_in[1];
    const float* bias = (const float*)d_in[2];
    const float* sign = (const float*)d_in[3];
    float* out = (float*)d_out;

    morpho_kernel<<<1024, 256, 0, stream>>>(x, w, bias, sign, out);
}